// Round 1
// baseline (422.777 us; speedup 1.0000x reference)
//
#include <hip/hip_runtime.h>
#include <hip/hip_bf16.h>
#include <math.h>

typedef __bf16 bf16x8 __attribute__((ext_vector_type(8)));
typedef float f32x4 __attribute__((ext_vector_type(4)));
typedef unsigned short u16x8 __attribute__((ext_vector_type(8)));

#define DEV __device__ __forceinline__

DEV unsigned short f2bf(float f){ __hip_bfloat16 h=__float2bfloat16(f); unsigned short u; __builtin_memcpy(&u,&h,2); return u; }
DEV float bf2f(unsigned short u){ __hip_bfloat16 h; __builtin_memcpy(&h,&u,2); return __bfloat162float(h); }
DEV float gelu_f(float v){ return 0.5f*v*(1.0f+erff(v*0.70710678118654752f)); }

DEV void gl2lds16(const void* g, void* l){
  __builtin_amdgcn_global_load_lds((const __attribute__((address_space(1))) void*)g,
                                   (__attribute__((address_space(3))) void*)l, 16, 0, 0);
}

// ---- weight transpose: WT[n][k] (bf16) = W[k][n] (f32); i indexes WT flat.
__global__ __launch_bounds__(256) void k_wt(const float* __restrict__ W,
                                            unsigned short* __restrict__ WT,
                                            int K, int N){
  int i = blockIdx.x*256 + threadIdx.x;
  if (i >= K*N) return;
  int k = i % K, n = i / K;
  WT[i] = f2bf(W[(size_t)k*N + n]);
}

// ---- LN1: x[b][p][c] (f32) -> ht[b][c][p] (bf16, layernormed rows over c)
__global__ __launch_bounds__(256) void k_ln1(const float* __restrict__ x,
                                             const float* __restrict__ g,
                                             const float* __restrict__ be,
                                             unsigned short* __restrict__ ht){
  __shared__ unsigned short tile[32][512];
  int blk = blockIdx.x;
  int b = blk >> 3, p0 = (blk & 7) << 5;
  int tid = threadIdx.x, w = tid >> 6, l = tid & 63;
  float4 gv0 = *(const float4*)(g  + l*8);
  float4 gv1 = *(const float4*)(g  + l*8 + 4);
  float4 bv0 = *(const float4*)(be + l*8);
  float4 bv1 = *(const float4*)(be + l*8 + 4);
  const float* xb = x + (((size_t)b << 8) + p0) * 512;
  for (int i = 0; i < 8; ++i) {
    int pl = (i << 2) + w;                 // wave w handles rows w, w+4, ...
    const float* row = xb + (size_t)pl*512 + l*8;
    float4 v0 = *(const float4*)row;
    float4 v1 = *(const float4*)(row + 4);
    float s  = v0.x+v0.y+v0.z+v0.w + v1.x+v1.y+v1.z+v1.w;
    float s2 = v0.x*v0.x+v0.y*v0.y+v0.z*v0.z+v0.w*v0.w
             + v1.x*v1.x+v1.y*v1.y+v1.z*v1.z+v1.w*v1.w;
    #pragma unroll
    for (int off = 32; off; off >>= 1){ s += __shfl_xor(s, off); s2 += __shfl_xor(s2, off); }
    float mu = s * (1.0f/512.0f);
    float rs = rsqrtf(s2*(1.0f/512.0f) - mu*mu + 1e-6f);
    u16x8 o;
    o[0]=f2bf((v0.x-mu)*rs*gv0.x+bv0.x);
    o[1]=f2bf((v0.y-mu)*rs*gv0.y+bv0.y);
    o[2]=f2bf((v0.z-mu)*rs*gv0.z+bv0.z);
    o[3]=f2bf((v0.w-mu)*rs*gv0.w+bv0.w);
    o[4]=f2bf((v1.x-mu)*rs*gv1.x+bv1.x);
    o[5]=f2bf((v1.y-mu)*rs*gv1.y+bv1.y);
    o[6]=f2bf((v1.z-mu)*rs*gv1.z+bv1.z);
    o[7]=f2bf((v1.w-mu)*rs*gv1.w+bv1.w);
    *(u16x8*)(&tile[pl][l*8]) = o;
  }
  __syncthreads();
  unsigned short* hb = ht + ((size_t)b << 17);   // b * 512 * 256
  #pragma unroll
  for (int it = 0; it < 8; ++it) {
    int c = (it << 6) + (tid >> 2);
    int pch = (tid & 3) << 3;
    u16x8 o;
    #pragma unroll
    for (int j = 0; j < 8; ++j) o[j] = tile[pch + j][c];
    *(u16x8*)(hb + (size_t)c*256 + p0 + pch) = o;
  }
}

// ---- LN2: x2[m][c] (f32, m=(b,p)) -> h2[m][c] (bf16)
__global__ __launch_bounds__(256) void k_ln2(const float* __restrict__ x2,
                                             const float* __restrict__ g,
                                             const float* __restrict__ be,
                                             unsigned short* __restrict__ h2){
  int tid = threadIdx.x, w = tid >> 6, l = tid & 63;
  float4 gv0 = *(const float4*)(g  + l*8);
  float4 gv1 = *(const float4*)(g  + l*8 + 4);
  float4 bv0 = *(const float4*)(be + l*8);
  float4 bv1 = *(const float4*)(be + l*8 + 4);
  int wid = blockIdx.x*4 + w;
  for (int r = wid; r < 65536; r += gridDim.x*4) {
    const float* row = x2 + (size_t)r*512 + l*8;
    float4 v0 = *(const float4*)row;
    float4 v1 = *(const float4*)(row + 4);
    float s  = v0.x+v0.y+v0.z+v0.w + v1.x+v1.y+v1.z+v1.w;
    float s2 = v0.x*v0.x+v0.y*v0.y+v0.z*v0.z+v0.w*v0.w
             + v1.x*v1.x+v1.y*v1.y+v1.z*v1.z+v1.w*v1.w;
    #pragma unroll
    for (int off = 32; off; off >>= 1){ s += __shfl_xor(s, off); s2 += __shfl_xor(s2, off); }
    float mu = s * (1.0f/512.0f);
    float rs = rsqrtf(s2*(1.0f/512.0f) - mu*mu + 1e-6f);
    u16x8 o;
    o[0]=f2bf((v0.x-mu)*rs*gv0.x+bv0.x);
    o[1]=f2bf((v0.y-mu)*rs*gv0.y+bv0.y);
    o[2]=f2bf((v0.z-mu)*rs*gv0.z+bv0.z);
    o[3]=f2bf((v0.w-mu)*rs*gv0.w+bv0.w);
    o[4]=f2bf((v1.x-mu)*rs*gv1.x+bv1.x);
    o[5]=f2bf((v1.y-mu)*rs*gv1.y+bv1.y);
    o[6]=f2bf((v1.z-mu)*rs*gv1.z+bv1.z);
    o[7]=f2bf((v1.w-mu)*rs*gv1.w+bv1.w);
    *(u16x8*)(h2 + (size_t)r*512 + l*8) = o;
  }
}

// ---- transpose-add: x2[b][p][c] = t[b][c][p] + x[b][p][c]
__global__ __launch_bounds__(256) void k_tadd(const unsigned short* __restrict__ t,
                                              const float* __restrict__ x,
                                              float* __restrict__ x2){
  __shared__ float tl[64][65];
  int blk = blockIdx.x;
  int b = blk >> 5, rem = blk & 31;
  int c0 = (rem >> 2) << 6, p0 = (rem & 3) << 6;
  int tid = threadIdx.x;
  int cl = tid >> 2, pch = (tid & 3) << 4;
  const unsigned short* tp = t + (((size_t)b << 9) + c0 + cl)*256 + p0 + pch;
  u16x8 a0 = *(const u16x8*)tp;
  u16x8 a1 = *(const u16x8*)(tp + 8);
  #pragma unroll
  for (int j = 0; j < 8; ++j) tl[cl][pch + j]     = bf2f(a0[j]);
  #pragma unroll
  for (int j = 0; j < 8; ++j) tl[cl][pch + 8 + j] = bf2f(a1[j]);
  __syncthreads();
  int c = tid & 63, pr = (tid >> 6) << 4;
  size_t base = (((size_t)b << 8) + p0 + pr)*512 + c0 + c;
  #pragma unroll
  for (int k = 0; k < 16; ++k) {
    size_t o = base + (size_t)k*512;
    x2[o] = tl[c][pr + k] + x[o];
  }
}

// ---- GEMM: C[m][n] = epi(sum_k A[m][k]*BT[n][k] + bias[n])
// A: [M][K] bf16 row-major; BT: [N][K] bf16 row-major.
// MODE 0: outb[m][n] = bf16(v).  MODE 1: outf[m][n] = v + f32(h2[m][n]).
template<int GELU, int MODE>
__global__ __launch_bounds__(256) void k_gemm(
    const unsigned short* __restrict__ A,
    const unsigned short* __restrict__ BT,
    const float* __restrict__ bias,
    unsigned short* __restrict__ outb,
    float* __restrict__ outf,
    const unsigned short* __restrict__ h2,
    int M, int N, int K)
{
  __shared__ char lsA[16384];   // 128 rows x 128 B (64 bf16), xor-8 chunk swizzle
  __shared__ char lsB[16384];
  int tid = threadIdx.x;
  int nTn = N >> 7;
  int tm = blockIdx.x / nTn, tn = blockIdx.x - tm*nTn;
  int m0 = tm << 7, n0 = tn << 7;
  int w = tid >> 6, l = tid & 63;
  int wm = w >> 1, wn = w & 1;            // 2x2 wave grid, 64x64 per wave
  int la = l & 15, lg = l >> 4;
  f32x4 zero = {0.f, 0.f, 0.f, 0.f};
  f32x4 acc[4][4];
  #pragma unroll
  for (int i = 0; i < 4; ++i)
    #pragma unroll
    for (int j = 0; j < 4; ++j) acc[i][j] = zero;
  int sr = tid >> 3, sc = tid & 7;        // staging: 8 chunks of 16 B per row
  int KT = K >> 6;
  for (int kt = 0; kt < KT; ++kt) {
    int kb = kt << 6;
    #pragma unroll
    for (int q = 0; q < 4; ++q) {
      int rr = (q << 5) + sr;
      int c = sc ^ (rr & 7);              // inverse-swizzled global source
      gl2lds16(A  + (size_t)(m0 + rr)*K + kb + (c << 3), lsA + (q << 12) + tid*16);
      gl2lds16(BT + (size_t)(n0 + rr)*K + kb + (c << 3), lsB + (q << 12) + tid*16);
    }
    __syncthreads();
    #pragma unroll
    for (int ks = 0; ks < 2; ++ks) {
      bf16x8 af[4], bfr[4];
      #pragma unroll
      for (int mi = 0; mi < 4; ++mi){
        int rr = (wm << 6) + (mi << 4) + la;
        int c = (ks << 2) + lg;
        af[mi] = *(const bf16x8*)(lsA + rr*128 + ((c ^ (rr & 7)) << 4));
      }
      #pragma unroll
      for (int ni = 0; ni < 4; ++ni){
        int rr = (wn << 6) + (ni << 4) + la;
        int c = (ks << 2) + lg;
        bfr[ni] = *(const bf16x8*)(lsB + rr*128 + ((c ^ (rr & 7)) << 4));
      }
      #pragma unroll
      for (int mi = 0; mi < 4; ++mi)
        #pragma unroll
        for (int ni = 0; ni < 4; ++ni)
          acc[mi][ni] = __builtin_amdgcn_mfma_f32_16x16x32_bf16(af[mi], bfr[ni], acc[mi][ni], 0, 0, 0);
    }
    __syncthreads();
  }
  #pragma unroll
  for (int ni = 0; ni < 4; ++ni){
    int col = n0 + (wn << 6) + (ni << 4) + la;
    float bv = bias[col];
    #pragma unroll
    for (int mi = 0; mi < 4; ++mi){
      int rb = m0 + (wm << 6) + (mi << 4) + (lg << 2);
      #pragma unroll
      for (int rg = 0; rg < 4; ++rg){
        float v = acc[mi][ni][rg] + bv;
        if (GELU) v = gelu_f(v);
        size_t o = (size_t)(rb + rg)*N + col;
        if (MODE == 0) outb[o] = f2bf(v);
        else           outf[o] = v + bf2f(h2[o]);
      }
    }
  }
}

extern "C" void kernel_launch(void* const* d_in, const int* in_sizes, int n_in,
                              void* d_out, int out_size, void* d_ws, size_t ws_size,
                              hipStream_t stream) {
  const float* x   = (const float*)d_in[0];
  const float* lng = (const float*)d_in[1];
  const float* lnb = (const float*)d_in[2];
  const float* w1a = (const float*)d_in[3];
  const float* b1a = (const float*)d_in[4];
  const float* w1b = (const float*)d_in[5];
  const float* b1b = (const float*)d_in[6];
  const float* w2a = (const float*)d_in[7];
  const float* b2a = (const float*)d_in[8];
  const float* w2b = (const float*)d_in[9];
  const float* b2b = (const float*)d_in[10];
  float* out = (float*)d_out;
  char* ws = (char*)d_ws;
  unsigned short* bufA = (unsigned short*)ws;                       // 64 MiB
  unsigned short* bufB = (unsigned short*)(ws + (size_t)(64u << 20)); // 64 MiB
  unsigned short* wt1a = (unsigned short*)(ws + (size_t)(128u << 20));
  unsigned short* wt1b = wt1a + 256*256;
  unsigned short* wt2a = wt1b + 256*256;
  unsigned short* wt2b = wt2a + 512*512;

  // weight transposes (tiny)
  k_wt<<<256,  256, 0, stream>>>(w1a, wt1a, 256, 256);
  k_wt<<<256,  256, 0, stream>>>(w1b, wt1b, 256, 256);
  k_wt<<<1024, 256, 0, stream>>>(w2a, wt2a, 512, 512);
  k_wt<<<1024, 256, 0, stream>>>(w2b, wt2b, 512, 512);

  // token mixing
  k_ln1<<<2048, 256, 0, stream>>>(x, lng, lnb, bufA);                       // ht[b][c][p]
  k_gemm<1,0><<<2048, 256, 0, stream>>>(bufA, wt1a, b1a, bufB, nullptr, nullptr,
                                        131072, 256, 256);                  // u1
  k_gemm<0,0><<<2048, 256, 0, stream>>>(bufB, wt1b, b1b, bufA, nullptr, nullptr,
                                        131072, 256, 256);                  // t
  k_tadd<<<8192, 256, 0, stream>>>(bufA, x, out);                           // x2 in d_out

  // channel mixing
  k_ln2<<<2048, 256, 0, stream>>>(out, lng, lnb, bufB);                     // h2
  k_gemm<1,0><<<2048, 256, 0, stream>>>(bufB, wt2a, b2a, bufA, nullptr, nullptr,
                                        65536, 512, 512);                   // u2
  k_gemm<0,1><<<2048, 256, 0, stream>>>(bufA, wt2b, b2b, nullptr, out, bufB,
                                        65536, 512, 512);                   // out = h2 + t2
}

// Round 2
// 322.476 us; speedup vs baseline: 1.3110x; 1.3110x over previous
//
#include <hip/hip_runtime.h>
#include <hip/hip_bf16.h>
#include <math.h>

typedef __bf16 bf16x8 __attribute__((ext_vector_type(8)));
typedef float f32x4 __attribute__((ext_vector_type(4)));
typedef unsigned short u16x8 __attribute__((ext_vector_type(8)));

#define DEV __device__ __forceinline__

DEV unsigned short f2bf(float f){ __hip_bfloat16 h=__float2bfloat16(f); unsigned short u; __builtin_memcpy(&u,&h,2); return u; }
DEV float bf2f(unsigned short u){ __hip_bfloat16 h; __builtin_memcpy(&h,&u,2); return __bfloat162float(h); }

// tanh-form GELU: exp is HW (v_exp_f32), rcp is HW. ~10 VALU vs ~40+ for erff.
DEV float gelu_f(float v){
  float u = v*(0.7978845608f + 0.0356774081f*v*v);
  float e = __expf(2.0f*u);
  float t = 1.0f - 2.0f*__builtin_amdgcn_rcpf(e + 1.0f);
  return 0.5f*v*(1.0f + t);
}

DEV void gl2lds16(const void* g, void* l){
  __builtin_amdgcn_global_load_lds((const __attribute__((address_space(1))) void*)g,
                                   (__attribute__((address_space(3))) void*)l, 16, 0, 0);
}

// ---- weight transpose: WT[n][k] (bf16) = W[k][n] (f32)
__global__ __launch_bounds__(256) void k_wt(const float* __restrict__ W,
                                            unsigned short* __restrict__ WT,
                                            int K, int N){
  int i = blockIdx.x*256 + threadIdx.x;
  if (i >= K*N) return;
  int k = i % K, n = i / K;
  WT[i] = f2bf(W[(size_t)k*N + n]);
}

// ---- LN1 + transpose + bf16 x copy:
// x[b][p][c] f32 -> ht[b][c][p] bf16 (layernormed), xb[b][p][c] bf16 (raw copy)
__global__ __launch_bounds__(256) void k_ln1x(const float* __restrict__ x,
                                              const float* __restrict__ g,
                                              const float* __restrict__ be,
                                              unsigned short* __restrict__ ht,
                                              unsigned short* __restrict__ xb){
  __shared__ unsigned short tile[32][512];
  int blk = blockIdx.x;
  int b = blk >> 3, p0 = (blk & 7) << 5;
  int tid = threadIdx.x, w = tid >> 6, l = tid & 63;
  float4 gv0 = *(const float4*)(g  + l*8);
  float4 gv1 = *(const float4*)(g  + l*8 + 4);
  float4 bv0 = *(const float4*)(be + l*8);
  float4 bv1 = *(const float4*)(be + l*8 + 4);
  const float* xbase = x + (((size_t)b << 8) + p0) * 512;
  for (int i = 0; i < 8; ++i) {
    int pl = (i << 2) + w;
    const float* row = xbase + (size_t)pl*512 + l*8;
    float4 v0 = *(const float4*)row;
    float4 v1 = *(const float4*)(row + 4);
    // raw bf16 copy of x (coalesced)
    u16x8 rc;
    rc[0]=f2bf(v0.x); rc[1]=f2bf(v0.y); rc[2]=f2bf(v0.z); rc[3]=f2bf(v0.w);
    rc[4]=f2bf(v1.x); rc[5]=f2bf(v1.y); rc[6]=f2bf(v1.z); rc[7]=f2bf(v1.w);
    *(u16x8*)(xb + (((size_t)b << 8) + p0 + pl)*512 + l*8) = rc;
    float s  = v0.x+v0.y+v0.z+v0.w + v1.x+v1.y+v1.z+v1.w;
    float s2 = v0.x*v0.x+v0.y*v0.y+v0.z*v0.z+v0.w*v0.w
             + v1.x*v1.x+v1.y*v1.y+v1.z*v1.z+v1.w*v1.w;
    #pragma unroll
    for (int off = 32; off; off >>= 1){ s += __shfl_xor(s, off); s2 += __shfl_xor(s2, off); }
    float mu = s * (1.0f/512.0f);
    float rs = rsqrtf(s2*(1.0f/512.0f) - mu*mu + 1e-6f);
    u16x8 o;
    o[0]=f2bf((v0.x-mu)*rs*gv0.x+bv0.x);
    o[1]=f2bf((v0.y-mu)*rs*gv0.y+bv0.y);
    o[2]=f2bf((v0.z-mu)*rs*gv0.z+bv0.z);
    o[3]=f2bf((v0.w-mu)*rs*gv0.w+bv0.w);
    o[4]=f2bf((v1.x-mu)*rs*gv1.x+bv1.x);
    o[5]=f2bf((v1.y-mu)*rs*gv1.y+bv1.y);
    o[6]=f2bf((v1.z-mu)*rs*gv1.z+bv1.z);
    o[7]=f2bf((v1.w-mu)*rs*gv1.w+bv1.w);
    *(u16x8*)(&tile[pl][l*8]) = o;
  }
  __syncthreads();
  unsigned short* hb = ht + ((size_t)b << 17);   // b * 512 * 256
  #pragma unroll
  for (int it = 0; it < 8; ++it) {
    int c = (it << 6) + (tid >> 2);
    int pch = (tid & 3) << 3;
    u16x8 o;
    #pragma unroll
    for (int j = 0; j < 8; ++j) o[j] = tile[pch + j][c];
    *(u16x8*)(hb + (size_t)c*256 + p0 + pch) = o;
  }
}

// ---- transpose-add + LN2:  h2[b][p][c] = LN( t[b][c][p] + xb[b][p][c] )
__global__ __launch_bounds__(256) void k_tl2(const unsigned short* __restrict__ t,
                                             const unsigned short* __restrict__ xb,
                                             const float* __restrict__ g,
                                             const float* __restrict__ be,
                                             unsigned short* __restrict__ h2){
  __shared__ unsigned short th[32][520];   // pad: row stride 1040B (16B aligned)
  int blk = blockIdx.x;
  int b = blk >> 3, p0 = (blk & 7) << 5;
  int tid = threadIdx.x, w = tid >> 6, l = tid & 63;
  const unsigned short* tb = t + ((size_t)b << 17) + p0;
  #pragma unroll
  for (int it = 0; it < 8; ++it){
    int fc = (it << 8) + tid;            // 0..2047
    int c = fc >> 2, pch = (fc & 3) << 3;
    u16x8 tv = *(const u16x8*)(tb + (size_t)c*256 + pch);
    #pragma unroll
    for (int j = 0; j < 8; ++j) th[pch + j][c] = tv[j];
  }
  __syncthreads();
  float4 gv0 = *(const float4*)(g  + l*8);
  float4 gv1 = *(const float4*)(g  + l*8 + 4);
  float4 bv0 = *(const float4*)(be + l*8);
  float4 bv1 = *(const float4*)(be + l*8 + 4);
  #pragma unroll
  for (int it = 0; it < 8; ++it){
    int pl = (it << 2) + w;
    u16x8 tvv = *(const u16x8*)(&th[pl][l*8]);
    size_t rowo = (((size_t)b << 8) + p0 + pl)*512 + l*8;
    u16x8 xvv = *(const u16x8*)(xb + rowo);
    float v[8];
    #pragma unroll
    for (int j = 0; j < 8; ++j) v[j] = bf2f(tvv[j]) + bf2f(xvv[j]);
    float s = 0.f, s2 = 0.f;
    #pragma unroll
    for (int j = 0; j < 8; ++j){ s += v[j]; s2 += v[j]*v[j]; }
    #pragma unroll
    for (int off = 32; off; off >>= 1){ s += __shfl_xor(s, off); s2 += __shfl_xor(s2, off); }
    float mu = s * (1.0f/512.0f);
    float rs = rsqrtf(s2*(1.0f/512.0f) - mu*mu + 1e-6f);
    u16x8 o;
    o[0]=f2bf((v[0]-mu)*rs*gv0.x+bv0.x);
    o[1]=f2bf((v[1]-mu)*rs*gv0.y+bv0.y);
    o[2]=f2bf((v[2]-mu)*rs*gv0.z+bv0.z);
    o[3]=f2bf((v[3]-mu)*rs*gv0.w+bv0.w);
    o[4]=f2bf((v[4]-mu)*rs*gv1.x+bv1.x);
    o[5]=f2bf((v[5]-mu)*rs*gv1.y+bv1.y);
    o[6]=f2bf((v[6]-mu)*rs*gv1.z+bv1.z);
    o[7]=f2bf((v[7]-mu)*rs*gv1.w+bv1.w);
    *(u16x8*)(h2 + rowo) = o;
  }
}

// ---- stage a tile of R rows x 64 cols (bf16) into LDS with xor-8 chunk swizzle
template<int R>
DEV void stageTile(const unsigned short* src, int rowStride, char* ldst, int tid){
  #pragma unroll
  for (int i = 0; i < (R*8)/512; ++i){
    int q = (i << 9) + tid;
    int row = q >> 3, sc = q & 7;
    int cc = sc ^ (row & 7);
    gl2lds16(src + (size_t)row*rowStride + (cc << 3), ldst + q*16);
  }
}

// ---- fused MLP: out = (gelu(A @ W1 + b1)) @ W2 + b2 [+ A if MODE==1]
// A: [M][NT] bf16.  W1T/W2T: [NT][NT] bf16 ([n][k]).  MT rows per block, 512 thr.
// MODE 0: outb bf16.  MODE 1: outf f32 = result + f32(A).
template<int MT, int NT, int MODE>
__global__ __launch_bounds__(512, 2) void k_mlp(
    const unsigned short* __restrict__ A,
    const unsigned short* __restrict__ W1T,
    const unsigned short* __restrict__ W2T,
    const float* __restrict__ b1v,
    const float* __restrict__ b2v,
    unsigned short* __restrict__ outb,
    float* __restrict__ outf)
{
  constexpr int WN = NT/64;          // waves along n
  constexpr int KT = NT/64;          // 64-wide k tiles
  constexpr int CHR = NT/8;          // 16B chunks per U row
  __shared__ char lds[MT*128 + NT*128 + MT*NT*2];
  char* lsA = lds;
  char* lsW = lds + MT*128;
  char* U   = lds + MT*128 + NT*128;
  const int tid = threadIdx.x;
  const int w = tid >> 6, l = tid & 63;
  const int wm = w / WN, wn = w % WN;
  const int la = l & 15, lg = l >> 4;
  const size_t m0 = (size_t)blockIdx.x * MT;
  const unsigned short* Ab = A + m0*NT;

  f32x4 acc[4][4];
  #pragma unroll
  for (int i = 0; i < 4; ++i)
    #pragma unroll
    for (int j = 0; j < 4; ++j) acc[i][j] = (f32x4){0.f,0.f,0.f,0.f};

  // ---- stage 1: U = gelu(A @ W1 + b1)
  for (int kt = 0; kt < KT; ++kt){
    stageTile<MT>(Ab  + (kt << 6), NT, lsA, tid);
    stageTile<NT>(W1T + (kt << 6), NT, lsW, tid);
    __syncthreads();
    #pragma unroll
    for (int ks = 0; ks < 2; ++ks){
      bf16x8 af[4], bfr[4];
      int c = (ks << 2) + lg;
      #pragma unroll
      for (int mi = 0; mi < 4; ++mi){
        int rr = (wm << 6) + (mi << 4) + la;
        af[mi] = *(const bf16x8*)(lsA + rr*128 + ((c ^ (rr & 7)) << 4));
      }
      #pragma unroll
      for (int ni = 0; ni < 4; ++ni){
        int rn = (wn << 6) + (ni << 4) + la;
        bfr[ni] = *(const bf16x8*)(lsW + rn*128 + ((c ^ (rn & 7)) << 4));
      }
      #pragma unroll
      for (int mi = 0; mi < 4; ++mi)
        #pragma unroll
        for (int ni = 0; ni < 4; ++ni)
          acc[mi][ni] = __builtin_amdgcn_mfma_f32_16x16x32_bf16(af[mi], bfr[ni], acc[mi][ni], 0, 0, 0);
    }
    __syncthreads();
  }
  // gelu epilogue -> U (bf16, chunk-swizzled), reset acc
  #pragma unroll
  for (int ni = 0; ni < 4; ++ni){
    int col = (wn << 6) + (ni << 4) + la;
    float bv = b1v[col];
    #pragma unroll
    for (int mi = 0; mi < 4; ++mi){
      int rb = (wm << 6) + (mi << 4) + (lg << 2);
      #pragma unroll
      for (int rg = 0; rg < 4; ++rg){
        float v = gelu_f(acc[mi][ni][rg] + bv);
        int r = rb + rg;
        *(unsigned short*)(U + ((size_t)r*NT + ((((col >> 3) ^ (r & 7)) << 3) + (col & 7)))*2) = f2bf(v);
        acc[mi][ni][rg] = 0.0f;
      }
    }
  }
  __syncthreads();
  // ---- stage 2: acc = U @ W2
  for (int kt = 0; kt < KT; ++kt){
    stageTile<NT>(W2T + (kt << 6), NT, lsW, tid);
    __syncthreads();
    #pragma unroll
    for (int ks = 0; ks < 2; ++ks){
      bf16x8 af[4], bfr[4];
      int c = (ks << 2) + lg;
      int cki = (kt << 3) + c;
      #pragma unroll
      for (int mi = 0; mi < 4; ++mi){
        int rr = (wm << 6) + (mi << 4) + la;
        af[mi] = *(const bf16x8*)(U + (size_t)rr*NT*2 + ((cki ^ (rr & 7)) << 4));
      }
      #pragma unroll
      for (int ni = 0; ni < 4; ++ni){
        int rn = (wn << 6) + (ni << 4) + la;
        bfr[ni] = *(const bf16x8*)(lsW + rn*128 + ((c ^ (rn & 7)) << 4));
      }
      #pragma unroll
      for (int mi = 0; mi < 4; ++mi)
        #pragma unroll
        for (int ni = 0; ni < 4; ++ni)
          acc[mi][ni] = __builtin_amdgcn_mfma_f32_16x16x32_bf16(af[mi], bfr[ni], acc[mi][ni], 0, 0, 0);
    }
    __syncthreads();
  }
  // ---- final epilogue through U, then coalesced global write
  #pragma unroll
  for (int ni = 0; ni < 4; ++ni){
    int col = (wn << 6) + (ni << 4) + la;
    float bv = b2v[col];
    #pragma unroll
    for (int mi = 0; mi < 4; ++mi){
      int rb = (wm << 6) + (mi << 4) + (lg << 2);
      #pragma unroll
      for (int rg = 0; rg < 4; ++rg){
        float v = acc[mi][ni][rg] + bv;
        int r = rb + rg;
        *(unsigned short*)(U + ((size_t)r*NT + ((((col >> 3) ^ (r & 7)) << 3) + (col & 7)))*2) = f2bf(v);
      }
    }
  }
  __syncthreads();
  #pragma unroll
  for (int i = 0; i < (MT*CHR)/512; ++i){
    int q = (i << 9) + tid;
    int r = q / CHR, ck = q % CHR;
    u16x8 val = *(const u16x8*)(U + (size_t)r*NT*2 + ((ck ^ (r & 7)) << 4));
    size_t go = (m0 + r)*NT + (ck << 3);
    if (MODE == 0){
      *(u16x8*)(outb + go) = val;
    } else {
      u16x8 av = *(const u16x8*)(Ab + (size_t)r*NT + (ck << 3));
      float4 o0, o1;
      o0.x = bf2f(val[0]) + bf2f(av[0]);
      o0.y = bf2f(val[1]) + bf2f(av[1]);
      o0.z = bf2f(val[2]) + bf2f(av[2]);
      o0.w = bf2f(val[3]) + bf2f(av[3]);
      o1.x = bf2f(val[4]) + bf2f(av[4]);
      o1.y = bf2f(val[5]) + bf2f(av[5]);
      o1.z = bf2f(val[6]) + bf2f(av[6]);
      o1.w = bf2f(val[7]) + bf2f(av[7]);
      *(float4*)(outf + go)     = o0;
      *(float4*)(outf + go + 4) = o1;
    }
  }
}

extern "C" void kernel_launch(void* const* d_in, const int* in_sizes, int n_in,
                              void* d_out, int out_size, void* d_ws, size_t ws_size,
                              hipStream_t stream) {
  const float* x   = (const float*)d_in[0];
  const float* lng = (const float*)d_in[1];
  const float* lnb = (const float*)d_in[2];
  const float* w1a = (const float*)d_in[3];
  const float* b1a = (const float*)d_in[4];
  const float* w1b = (const float*)d_in[5];
  const float* b1b = (const float*)d_in[6];
  const float* w2a = (const float*)d_in[7];
  const float* b2a = (const float*)d_in[8];
  const float* w2b = (const float*)d_in[9];
  const float* b2b = (const float*)d_in[10];
  float* out = (float*)d_out;
  char* ws = (char*)d_ws;
  unsigned short* bufA = (unsigned short*)ws;                         // 64 MiB
  unsigned short* bufB = (unsigned short*)(ws + (size_t)(64u << 20)); // 64 MiB
  unsigned short* wt1a = (unsigned short*)(ws + (size_t)(128u << 20));
  unsigned short* wt1b = wt1a + 256*256;
  unsigned short* wt2a = wt1b + 256*256;
  unsigned short* wt2b = wt2a + 512*512;
  unsigned short* xb   = (unsigned short*)d_out;  // scratch in d_out's first 64 MiB
                                                  // (consumed by k_tl2 before final write)

  k_wt<<<256,  256, 0, stream>>>(w1a, wt1a, 256, 256);
  k_wt<<<256,  256, 0, stream>>>(w1b, wt1b, 256, 256);
  k_wt<<<1024, 256, 0, stream>>>(w2a, wt2a, 512, 512);
  k_wt<<<1024, 256, 0, stream>>>(w2b, wt2b, 512, 512);

  // token mixing: ht = LN1(x)^T ; t = gelu(ht@w1a+b1a)@w1b+b1b
  k_ln1x<<<2048, 256, 0, stream>>>(x, lng, lnb, bufA, xb);
  k_mlp<128, 256, 0><<<1024, 512, 0, stream>>>(bufA, wt1a, wt1b, b1a, b1b, bufB, nullptr);

  // residual + LN2 (x2 never materialized in f32)
  k_tl2<<<2048, 256, 0, stream>>>(bufB, xb, lng, lnb, bufA);

  // channel mixing: out = h2 + gelu(h2@w2a+b2a)@w2b+b2b
  k_mlp<64, 512, 1><<<1024, 512, 0, stream>>>(bufA, wt2a, wt2b, b2a, b2b, nullptr, out);
}